// Round 1
// 532.475 us; speedup vs baseline: 1.0765x; 1.0765x over previous
//
#include <hip/hip_runtime.h>

#define B_ 256
#define N_ 64
#define T_ 4096
#define H_ 16

#define GLOBAL_AS __attribute__((address_space(1)))
#define LDS_AS    __attribute__((address_space(3)))

__device__ __forceinline__ void async_copy16(const float* src, float* dst) {
  // global -> LDS direct copy, 16B per lane. LDS dest is wave-uniform base
  // + lane*16 (hardware rule); dst must be identical across the wave.
  __builtin_amdgcn_global_load_lds((const GLOBAL_AS void*)src,
                                   (LDS_AS void*)dst, 16, 0, 0);
}

// ---------- Kernel A: per-(b,n) variance over T — one wave per row ----------
__global__ __launch_bounds__(256) void k_var(const float* __restrict__ x,
                                             float* __restrict__ energy) {
  const int wid  = threadIdx.x >> 6;
  const int lane = threadIdx.x & 63;
  const int row  = blockIdx.x * 4 + wid;           // b*N + n
  const float* __restrict__ xr = x + (size_t)row * T_;
  float s = 0.f, ss = 0.f;
#pragma unroll
  for (int k = 0; k < 16; ++k) {                   // 16 independent float4 loads
    const float4 v = *(const float4*)(xr + (k * 64 + lane) * 4);
    s  += v.x + v.y + v.z + v.w;
    ss += v.x * v.x + v.y * v.y + v.z * v.z + v.w * v.w;
  }
#pragma unroll
  for (int off = 32; off > 0; off >>= 1) {
    s  += __shfl_down(s, off, 64);
    ss += __shfl_down(ss, off, 64);
  }
  if (lane == 0) {
    const float m = s * (1.0f / T_);
    energy[row] = ss * (1.0f / T_) - m * m;
  }
}

// ---------- Kernel B: analytic softmax attention weights ----------
// logit = beta_i * e_j with beta_i = 0.25*(c1*e_i + c3); row-constant terms
// cancel under softmax. Diagonal weight is exactly 0.
__global__ __launch_bounds__(64) void k_attn(const float* __restrict__ energy,
                                             const float* __restrict__ Wq,
                                             const float* __restrict__ bq,
                                             const float* __restrict__ Wk,
                                             const float* __restrict__ bk,
                                             float* __restrict__ attn) {
  const int b = blockIdx.x;
  const int i = threadIdx.x;                  // 0..63 (one wave)
  __shared__ float e[N_];
  __shared__ float wrow[N_][N_ + 1];
  e[i] = energy[b * N_ + i];
  float c1 = 0.f, c3 = 0.f;
#pragma unroll
  for (int h = 0; h < H_; ++h) { c1 += Wq[h] * Wk[h]; c3 += bq[h] * Wk[h]; }
  __syncthreads();
  const float beta = 0.25f * (c1 * e[i] + c3);   // scale = H^-0.5 = 0.25
  float l[N_];
  float mx = -3.0e38f;
#pragma unroll
  for (int j = 0; j < N_; ++j) {
    float lj = beta * e[j];
    if (j == i) lj = -3.0e38f;
    l[j] = lj;
    mx = fmaxf(mx, lj);
  }
  float sum = 0.f;
#pragma unroll
  for (int j = 0; j < N_; ++j) {
    float ex = (j == i) ? 0.f : __expf(l[j] - mx);
    l[j] = ex;
    sum += ex;
  }
  const float inv = 1.0f / sum;
#pragma unroll
  for (int j = 0; j < N_; ++j) wrow[i][j] = l[j] * inv;
  __syncthreads();
  float* __restrict__ ab = attn + (size_t)b * (N_ * N_);
#pragma unroll
  for (int r = 0; r < N_; ++r) ab[r * N_ + i] = wrow[r][i];
}

// ---------- Kernel C: out[b,i,t] = sum_j (w[b,i,j] + delta_ij) * x[b,j,t] ----
__device__ __forceinline__ void fma4(float4& a, float w, const float4& v) {
  a.x = fmaf(w, v.x, a.x);
  a.y = fmaf(w, v.y, a.y);
  a.z = fmaf(w, v.z, a.z);
  a.w = fmaf(w, v.w, a.w);
}

// Block: one b, one 512-wide t-tile. 512 threads = 8 waves; wave owns 8 i-rows.
// x tile (64 rows x 512 t = 128 KB) streamed once through LDS in 8 groups of
// 8 rows, double-buffered via global_load_lds (async; hidden under FMAs).
__global__ __launch_bounds__(512, 4) void k_out(const float* __restrict__ x,
                                                const float* __restrict__ attn,
                                                float* __restrict__ out) {
  const int b  = blockIdx.x >> 3;
  const int tt = blockIdx.x & 7;              // 8 tiles of 512 t-columns
  const int tid  = threadIdx.x;
  const int lane = tid & 63;
  const int wid  = tid >> 6;                  // 0..7

  __shared__ float wt[N_ * N_];               // wt[j*64 + i] = w[i][j] (+1 diag)
  __shared__ float xs[2][8 * 512];            // double buffer: 8 rows x 512 t

  // ---- stage w^T, conflict-free writes (64 consecutive-i lanes per store) ----
  const float* __restrict__ ab = attn + (size_t)b * (N_ * N_);
#pragma unroll
  for (int k = 0; k < 2; ++k) {
    const int idx = k * 512 + tid;            // 0..1023
    const int i  = idx & 63;
    const int jq = idx >> 6;                  // 0..15
    float4 v = *(const float4*)(ab + i * N_ + jq * 4);
    const int dj = i - jq * 4;                // residual: w'[i][i] += 1
    if      (dj == 0) v.x += 1.0f;
    else if (dj == 1) v.y += 1.0f;
    else if (dj == 2) v.z += 1.0f;
    else if (dj == 3) v.w += 1.0f;
    wt[(jq * 4 + 0) * N_ + i] = v.x;
    wt[(jq * 4 + 1) * N_ + i] = v.y;
    wt[(jq * 4 + 2) * N_ + i] = v.z;
    wt[(jq * 4 + 3) * N_ + i] = v.w;
  }

  // ---- async x staging: group g = rows 8g..8g+7, each 512 floats ----
  const float* __restrict__ xb = x + (size_t)b * (N_ * T_) + tt * 512;
  const int srow  = wid >> 1;                 // 0..3
  const int shalf = (wid & 1) * 256;          // which half-row this wave stages
  const float* srcl = xb + shalf + lane * 4;

  // prologue: stage group 0 into buffer 0
#pragma unroll
  for (int c = 0; c < 2; ++c) {
    const int jj = c * 4 + srow;
    async_copy16(srcl + (size_t)jj * T_, &xs[0][jj * 512 + shalf]);
  }
  __syncthreads();                            // drains vmcnt -> group 0 ready

  const int ibase = wid << 3;                 // this wave's 8 i-rows
  float4 acc[8][2];
#pragma unroll
  for (int ii = 0; ii < 8; ++ii) {
    acc[ii][0] = make_float4(0.f, 0.f, 0.f, 0.f);
    acc[ii][1] = make_float4(0.f, 0.f, 0.f, 0.f);
  }

  for (int g = 0; g < 8; ++g) {
    // issue next group's loads first (they fly during this group's FMAs)
    if (g < 7) {
      const int nb = (g + 1) & 1;
#pragma unroll
      for (int c = 0; c < 2; ++c) {
        const int jj = c * 4 + srow;
        async_copy16(srcl + (size_t)((g + 1) * 8 + jj) * T_,
                     &xs[nb][jj * 512 + shalf]);
      }
    }
    const float* __restrict__ xcur = &xs[g & 1][0];
#pragma unroll
    for (int jj = 0; jj < 8; ++jj) {
      const int j = g * 8 + jj;
      const float4 xa = *(const float4*)(xcur + jj * 512 + lane * 4);
      const float4 xc = *(const float4*)(xcur + jj * 512 + 256 + lane * 4);
      const float4 wa = *(const float4*)(&wt[j * N_ + ibase]);
      const float4 wb = *(const float4*)(&wt[j * N_ + ibase + 4]);
      fma4(acc[0][0], wa.x, xa); fma4(acc[0][1], wa.x, xc);
      fma4(acc[1][0], wa.y, xa); fma4(acc[1][1], wa.y, xc);
      fma4(acc[2][0], wa.z, xa); fma4(acc[2][1], wa.z, xc);
      fma4(acc[3][0], wa.w, xa); fma4(acc[3][1], wa.w, xc);
      fma4(acc[4][0], wb.x, xa); fma4(acc[4][1], wb.x, xc);
      fma4(acc[5][0], wb.y, xa); fma4(acc[5][1], wb.y, xc);
      fma4(acc[6][0], wb.z, xa); fma4(acc[6][1], wb.z, xc);
      fma4(acc[7][0], wb.w, xa); fma4(acc[7][1], wb.w, xc);
    }
    // one barrier per group: (a) next group's staging complete (implicit
    // vmcnt drain), (b) everyone done reading xs[g&1] before it is restaged.
    __syncthreads();
  }

  // ---- epilogue: pure stores (residual already folded into wt diagonal) ----
  float* __restrict__ ob = out + (size_t)b * (N_ * T_) + tt * 512;
#pragma unroll
  for (int ii = 0; ii < 8; ++ii) {
    const int i = ibase + ii;
    *(float4*)(ob + (size_t)i * T_ + lane * 4)       = acc[ii][0];
    *(float4*)(ob + (size_t)i * T_ + 256 + lane * 4) = acc[ii][1];
  }
}

extern "C" void kernel_launch(void* const* d_in, const int* in_sizes, int n_in,
                              void* d_out, int out_size, void* d_ws, size_t ws_size,
                              hipStream_t stream) {
  const float* x  = (const float*)d_in[0];
  const float* Wq = (const float*)d_in[1];
  const float* bq = (const float*)d_in[2];
  const float* Wk = (const float*)d_in[3];
  const float* bk = (const float*)d_in[4];
  float* out  = (float*)d_out;
  float* attn = out + (size_t)B_ * N_ * T_;
  // Stash energy in the out region (overwritten later by k_out) to avoid
  // assuming anything about ws_size. Stream order guarantees correctness.
  float* energy = out;
  hipLaunchKernelGGL(k_var, dim3(B_ * N_ / 4), dim3(256), 0, stream, x, energy);
  hipLaunchKernelGGL(k_attn, dim3(B_), dim3(64), 0, stream,
                     energy, Wq, bq, Wk, bk, attn);
  hipLaunchKernelGGL(k_out, dim3(B_ * 8), dim3(512), 0, stream, x, attn, out);
}

// Round 3
// 528.969 us; speedup vs baseline: 1.0837x; 1.0066x over previous
//
#include <hip/hip_runtime.h>

#define B_ 256
#define N_ 64
#define T_ 4096
#define H_ 16

typedef float f32x4 __attribute__((ext_vector_type(4)));

// ---------- Kernel A: per-(b,n) variance over T — one wave per row ----------
__global__ __launch_bounds__(256) void k_var(const float* __restrict__ x,
                                             float* __restrict__ energy) {
  const int wid  = threadIdx.x >> 6;
  const int lane = threadIdx.x & 63;
  const int row  = blockIdx.x * 4 + wid;           // b*N + n
  const float* __restrict__ xr = x + (size_t)row * T_;
  float s = 0.f, ss = 0.f;
#pragma unroll
  for (int k = 0; k < 16; ++k) {                   // 16 independent float4 loads
    const float4 v = *(const float4*)(xr + (k * 64 + lane) * 4);
    s  += v.x + v.y + v.z + v.w;
    ss += v.x * v.x + v.y * v.y + v.z * v.z + v.w * v.w;
  }
#pragma unroll
  for (int off = 32; off > 0; off >>= 1) {
    s  += __shfl_down(s, off, 64);
    ss += __shfl_down(ss, off, 64);
  }
  if (lane == 0) {
    const float m = s * (1.0f / T_);
    energy[row] = ss * (1.0f / T_) - m * m;
  }
}

// ---------- Kernel B (fallback path only): analytic softmax attention ----------
__global__ __launch_bounds__(64) void k_attn(const float* __restrict__ energy,
                                             const float* __restrict__ Wq,
                                             const float* __restrict__ bq,
                                             const float* __restrict__ Wk,
                                             const float* __restrict__ bk,
                                             float* __restrict__ attn) {
  const int b = blockIdx.x;
  const int i = threadIdx.x;                  // 0..63 (one wave)
  __shared__ float e[N_];
  __shared__ float wrow[N_][N_ + 1];
  e[i] = energy[b * N_ + i];
  float c1 = 0.f, c3 = 0.f;
#pragma unroll
  for (int h = 0; h < H_; ++h) { c1 += Wq[h] * Wk[h]; c3 += bq[h] * Wk[h]; }
  __syncthreads();
  const float beta = 0.25f * (c1 * e[i] + c3);   // scale = H^-0.5 = 0.25
  float l[N_];
  float mx = -3.0e38f;
#pragma unroll
  for (int j = 0; j < N_; ++j) {
    float lj = beta * e[j];
    if (j == i) lj = -3.0e38f;
    l[j] = lj;
    mx = fmaxf(mx, lj);
  }
  float sum = 0.f;
#pragma unroll
  for (int j = 0; j < N_; ++j) {
    float ex = (j == i) ? 0.f : __expf(l[j] - mx);
    l[j] = ex;
    sum += ex;
  }
  const float inv = 1.0f / sum;
#pragma unroll
  for (int j = 0; j < N_; ++j) wrow[i][j] = l[j] * inv;
  __syncthreads();
  float* __restrict__ ab = attn + (size_t)b * (N_ * N_);
#pragma unroll
  for (int r = 0; r < N_; ++r) ab[r * N_ + i] = wrow[r][i];
}

// ---------- shared main loop: out[b,i,t] = sum_j wt[j][i] * x[b,j,t] ----------
__device__ __forceinline__ void fma4(float4& a, float w, const float4& v) {
  a.x = fmaf(w, v.x, a.x);
  a.y = fmaf(w, v.y, a.y);
  a.z = fmaf(w, v.z, a.z);
  a.w = fmaf(w, v.w, a.w);
}

// wt[j*64+i] must hold softmax w[i][j] + (i==j ? 1 : 0).
// Block covers all 64 i-rows at one 256-float t-chunk. Wave = 8 i-rows.
// All waves stream the same x columns global->reg (L1-served after first wave);
// no barriers, no LDS staging in the main loop.
__device__ __forceinline__ void out_mainloop(const float* __restrict__ x,
                                             float* __restrict__ out,
                                             const float* __restrict__ wt,
                                             int b, int tt, int tid) {
  const int lane = tid & 63;
  const int wid  = tid >> 6;
  const int ibase = wid << 3;

  const float* __restrict__ xb =
      x + (size_t)b * (N_ * T_) + tt * 256 + lane * 4;

  float4 acc[8];
#pragma unroll
  for (int ii = 0; ii < 8; ++ii) acc[ii] = make_float4(0.f, 0.f, 0.f, 0.f);

#pragma unroll 4
  for (int j = 0; j < N_; ++j) {
    const float4 xv = *(const float4*)(xb + (size_t)j * T_);
    const float4 wa = *(const float4*)(&wt[j * N_ + ibase]);
    const float4 wb = *(const float4*)(&wt[j * N_ + ibase + 4]);
    fma4(acc[0], wa.x, xv); fma4(acc[1], wa.y, xv);
    fma4(acc[2], wa.z, xv); fma4(acc[3], wa.w, xv);
    fma4(acc[4], wb.x, xv); fma4(acc[5], wb.y, xv);
    fma4(acc[6], wb.z, xv); fma4(acc[7], wb.w, xv);
  }

  float* __restrict__ ob =
      out + (size_t)b * (N_ * T_) + tt * 256 + lane * 4;
#pragma unroll
  for (int ii = 0; ii < 8; ++ii) {
    __builtin_nontemporal_store(*(const f32x4*)&acc[ii],
        (f32x4*)(ob + (size_t)(ibase + ii) * T_));
  }
}

// ---------- Kernel C (primary): fused softmax + out ----------
__global__ __launch_bounds__(512, 4) void k_fused(const float* __restrict__ x,
                                                  const float* __restrict__ energy,
                                                  const float* __restrict__ Wq,
                                                  const float* __restrict__ bq,
                                                  const float* __restrict__ Wk,
                                                  const float* __restrict__ bk,
                                                  float* __restrict__ out,
                                                  float* __restrict__ attn) {
  const int b  = blockIdx.x >> 4;
  const int tt = blockIdx.x & 15;             // 16 chunks of 256 t-columns
  const int tid  = threadIdx.x;
  const int lane = tid & 63;
  const int wid  = tid >> 6;

  __shared__ float e[N_];
  __shared__ float wt[N_ * N_];               // wt[j*64+i] = w[i][j] (+1 diag)

  if (tid < N_) e[tid] = energy[b * N_ + tid];
  float c1 = 0.f, c3 = 0.f;
#pragma unroll
  for (int h = 0; h < H_; ++h) { c1 += Wq[h] * Wk[h]; c3 += bq[h] * Wk[h]; }
  __syncthreads();

  // thread -> (row i, j-chunk of 8): i = wid*8 + lane/8, j = (lane&7)*8 + c.
  // Row-wide max/sum via shfl_xor over the 8 lanes sharing i.
  const int i  = (wid << 3) + (lane >> 3);
  const int jg = lane & 7;
  const float beta = 0.25f * (c1 * e[i] + c3);   // scale = H^-0.5 = 0.25
  float l[8];
  float mx = -3.0e38f;
#pragma unroll
  for (int c = 0; c < 8; ++c) {
    const int j = (jg << 3) + c;
    const float lj = (j == i) ? -3.0e38f : beta * e[j];
    l[c] = lj;
    mx = fmaxf(mx, lj);
  }
#pragma unroll
  for (int off = 1; off < 8; off <<= 1) mx = fmaxf(mx, __shfl_xor(mx, off, 64));
  float sum = 0.f;
#pragma unroll
  for (int c = 0; c < 8; ++c) {
    const int j = (jg << 3) + c;
    const float ex = (j == i) ? 0.f : __expf(l[c] - mx);
    l[c] = ex;
    sum += ex;
  }
#pragma unroll
  for (int off = 1; off < 8; off <<= 1) sum += __shfl_xor(sum, off, 64);
  const float inv = 1.0f / sum;
#pragma unroll
  for (int c = 0; c < 8; ++c) {
    const int j = (jg << 3) + c;
    const float w = l[c] * inv;
    l[c] = w;
    wt[j * N_ + i] = w + ((j == i) ? 1.0f : 0.f);  // residual folded in
  }
  if (tt == 0) {                              // one block per b emits attn
    float* __restrict__ ar = attn + (size_t)b * (N_ * N_) + i * N_ + (jg << 3);
#pragma unroll
    for (int c = 0; c < 8; ++c) ar[c] = l[c];
  }
  __syncthreads();

  out_mainloop(x, out, wt, b, tt, tid);
}

// ---------- Kernel C' (fallback): wt from global attn ----------
__global__ __launch_bounds__(512, 4) void k_out2(const float* __restrict__ x,
                                                 const float* __restrict__ attn,
                                                 float* __restrict__ out) {
  const int b  = blockIdx.x >> 4;
  const int tt = blockIdx.x & 15;
  const int tid = threadIdx.x;

  __shared__ float wt[N_ * N_];
  const float* __restrict__ ab = attn + (size_t)b * (N_ * N_);
#pragma unroll
  for (int k = 0; k < 2; ++k) {
    const int idx = k * 512 + tid;            // 0..1023
    const int i  = idx & 63;
    const int jq = idx >> 6;                  // 0..15
    float4 v = *(const float4*)(ab + i * N_ + jq * 4);
    const int dj = i - jq * 4;                // residual: w'[i][i] += 1
    if      (dj == 0) v.x += 1.0f;
    else if (dj == 1) v.y += 1.0f;
    else if (dj == 2) v.z += 1.0f;
    else if (dj == 3) v.w += 1.0f;
    wt[(jq * 4 + 0) * N_ + i] = v.x;
    wt[(jq * 4 + 1) * N_ + i] = v.y;
    wt[(jq * 4 + 2) * N_ + i] = v.z;
    wt[(jq * 4 + 3) * N_ + i] = v.w;
  }
  __syncthreads();

  out_mainloop(x, out, wt, b, tt, tid);
}

extern "C" void kernel_launch(void* const* d_in, const int* in_sizes, int n_in,
                              void* d_out, int out_size, void* d_ws, size_t ws_size,
                              hipStream_t stream) {
  const float* x  = (const float*)d_in[0];
  const float* Wq = (const float*)d_in[1];
  const float* bq = (const float*)d_in[2];
  const float* Wk = (const float*)d_in[3];
  const float* bk = (const float*)d_in[4];
  float* out  = (float*)d_out;
  float* attn = out + (size_t)B_ * N_ * T_;

  if (d_ws != nullptr && ws_size >= (size_t)B_ * N_ * sizeof(float)) {
    // Primary path: energy lives in the workspace; attn computed in-block.
    float* energy = (float*)d_ws;
    hipLaunchKernelGGL(k_var, dim3(B_ * N_ / 4), dim3(256), 0, stream, x, energy);
    hipLaunchKernelGGL(k_fused, dim3(B_ * 16), dim3(512), 0, stream,
                       x, energy, Wq, bq, Wk, bk, out, attn);
  } else {
    // Fallback: energy aliased into out (overwritten later, stream-ordered).
    float* energy = out;
    hipLaunchKernelGGL(k_var, dim3(B_ * N_ / 4), dim3(256), 0, stream, x, energy);
    hipLaunchKernelGGL(k_attn, dim3(B_), dim3(64), 0, stream,
                       energy, Wq, bq, Wk, bk, attn);
    hipLaunchKernelGGL(k_out2, dim3(B_ * 16), dim3(512), 0, stream, x, attn, out);
  }
}